// Round 14
// baseline (30.913 us; speedup 1.0000x reference)
//
#include <hip/hip_runtime.h>
#include <stdint.h>

#define WW 19
#define NP 361
#define M19 0x7FFFFu
#define BPW 3                 // boards per wave in row phase (3*19 = 57 lanes)
#define BPB 12                // boards per chunk
#define TPB 256
#define STGF (BPB * 722)      // 8664 staged floats per buffer
#define P64 40                // u64 stride per board: 19 lib + 19 lg + 2 pad
#define GRID 512

typedef float f32x4 __attribute__((ext_vector_type(4)));

__device__ __forceinline__ uint32_t rev19(uint32_t x) { return __brev(x) >> 13; }

// Fill every horizontal run of m containing a seed of g (g subset of m).
__device__ __forceinline__ uint32_t runfill(uint32_t g, uint32_t m) {
  const uint32_t up = g | (m & ((m + g) ^ m ^ g));
  const uint32_t rm = rev19(m);
  const uint32_t rg = rev19(g);
  const uint32_t dn = rg | (rm & ((rm + rg) ^ rm ^ rg));
  return up | rev19(dn);
}

// Bit-spread: 19-bit mask -> every 3rd bit (Morton-3).
__device__ __forceinline__ uint64_t spr3(uint32_t v) {
  uint64_t x = v;
  x = (x | (x << 32)) & 0x1f00000000ffffull;
  x = (x | (x << 16)) & 0x1f0000ff0000ffull;
  x = (x | (x << 8)) & 0x100f00f00f00f00full;
  x = (x | (x << 4)) & 0x10c30c30c30c30c3ull;
  x = (x | (x << 2)) & 0x1249249249249249ull;
  return x;
}
// Bit-spread: 19-bit mask -> every 2nd bit (Morton-2).
__device__ __forceinline__ uint64_t spr2(uint32_t v) {
  uint64_t x = v;
  x = (x | (x << 16)) & 0x0000ffff0000ffffull;
  x = (x | (x << 8)) & 0x00ff00ff00ff00ffull;
  x = (x | (x << 4)) & 0x0f0f0f0f0f0f0f0full;
  x = (x | (x << 2)) & 0x3333333333333333ull;
  x = (x | (x << 1)) & 0x5555555555555555ull;
  return x;
}

// Persistent-ish blocks; grid-stride over chunks with a 2-deep LDS
// double-buffered global_load_lds pipeline: chunk i+1's loads are in flight
// while chunk i computes and stores. One full __syncthreads per chunk; the
// mid-chunk plane barrier is lgkmcnt-only so it does NOT drain the prefetch.
__global__ __launch_bounds__(TPB, 2) void go_pipe(
    const float* __restrict__ stones, const int* __restrict__ cur,
    const int* __restrict__ ko, const int* __restrict__ zob,
    const int* __restrict__ zturn, const int* __restrict__ phash,
    float* __restrict__ out, int B) {
  __shared__ float stg[2][STGF];        // double-buffered staged stone floats
  __shared__ uint64_t pl64[BPB * P64];  // packed planes (reused per chunk)

  const int wid = threadIdx.x >> 6;
  const int lane = threadIdx.x & 63;
  const size_t NB = (size_t)B * NP;
  const int NCH = (B + BPB - 1) / BPB;

  if (blockIdx.x >= (unsigned)NCH) return;

  // Zobrist tables preloaded into registers (uniform across blocks, cached).
  int zb[6], zw[6];
#pragma unroll
  for (int i = 0; i < 6; ++i) {
    const int p = i * 64 + lane;
    zb[i] = (p < NP) ? zob[p] : 0;
    zw[i] = (p < NP) ? zob[NP + p] : 0;
  }
  const int zt = zturn[0] ^ zturn[1];

  // Stage chunk cc into LDS buffer `buf` (async, zero VGPR round-trip).
  auto stage = [&](int buf, int cc) {
    const int nbc = min(BPB, B - cc * BPB);
    const uint32_t nfl = (uint32_t)nbc * 722u;
    const float* gsrc = stones + (size_t)cc * BPB * 722;
#pragma unroll
    for (int rnd = 0; rnd < 9; ++rnd) {
      const uint32_t fo = (uint32_t)rnd * 1024u + (uint32_t)wid * 256u +
                          (uint32_t)lane * 4u;
      if (fo < nfl) {
        __builtin_amdgcn_global_load_lds(
            (const __attribute__((address_space(1))) uint32_t*)(gsrc + fo),
            (__attribute__((address_space(3))) uint32_t*)(&stg[buf][0] +
                                                          rnd * 1024 +
                                                          wid * 256),
            16, 0, 0);
      }
    }
  };

  // Prologue: stage first chunk, wait for it.
  stage(0, blockIdx.x);
  __syncthreads();

  int bufc = 0;
  for (int c = blockIdx.x; c < NCH; c += GRID) {
    const int b0 = c * BPB;
    const int nb = min(BPB, B - b0);
    const float* sbuf = &stg[bufc][0];

    // ---- issue next chunk's prefetch FIRST (hides under compute+store) ----
    if (c + GRID < NCH) stage(bufc ^ 1, c + GRID);

    // ---- hash from staged floats ------------------------------------------
    {
      int hv[BPW];
#pragma unroll
      for (int k = 0; k < BPW; ++k) {
        const int lb = wid * BPW + k;
        const int base = lb * 722;
        int h = 0;
#pragma unroll
        for (int i = 0; i < 6; ++i) {
          const int cc2 = i * 64 + lane;
          if (cc2 < NP) {
            const uint32_t sb = sbuf[base + cc2] > 0.5f;
            const uint32_t sw = sbuf[base + 361 + cc2] > 0.5f;
            h ^= zb[i] & -(int)sb;
            h ^= zw[i] & -(int)sw;
          }
        }
        hv[k] = h;
      }
#pragma unroll
      for (int off = 32; off > 0; off >>= 1) {
#pragma unroll
        for (int k = 0; k < BPW; ++k) hv[k] ^= __shfl_xor(hv[k], off, 64);
      }
      if (lane == 0) {
#pragma unroll
        for (int k = 0; k < BPW; ++k) {
          const int b = b0 + wid * BPW + k;
          if (b < B) out[3 * NB + b] = (float)(phash[b] ^ hv[k] ^ zt);
        }
      }
    }

    // ---- row-per-lane algebra + flood -> packed planes --------------------
    {
      const int k = (lane * 27) >> 9;  // lane / 19
      const int r = lane - k * WW;
      const int lb = wid * BPW + k;
      const int b = b0 + lb;
      const bool vl = (lane < 57) && (lb < nb);
      const int lbs = vl ? lb : 0;

      uint32_t brow = 0, wrow = 0;
      {
        const float* rb = &sbuf[lbs * 722 + r * WW];
#pragma unroll
        for (int cc2 = 0; cc2 < WW; ++cc2) {
          brow |= (uint32_t)(rb[cc2] > 0.5f) << cc2;
          wrow |= (uint32_t)(rb[361 + cc2] > 0.5f) << cc2;
        }
      }
      const int cp = vl ? cur[b] : 0;
      int2 kk = {-1, -1};
      if (vl) kk = ((const int2*)ko)[b];
      uint32_t mrow = (cp == 0) ? wrow : brow;
      uint32_t erow = ~(brow | wrow) & M19;
      if (!vl) { mrow = 0; erow = 0; }

      uint32_t t;
      t = __shfl(erow, lane - 1, 64);
      const uint32_t eu = (r > 0) ? t : 0u;
      t = __shfl(erow, lane + 1, 64);
      const uint32_t ed = (r < 18) ? t : 0u;
      const uint32_t el = (erow << 1) & M19;
      const uint32_t er_ = erow >> 1;
      const uint32_t s1 = eu ^ ed, c1 = eu & ed;
      const uint32_t s2 = el ^ er_, c2 = el & er_;
      const uint32_t cc = s1 & s2;
      const uint32_t L0 = s1 ^ s2;
      const uint32_t L1 = c1 ^ c2 ^ cc;
      const uint32_t L2 = (c1 & c2) | (cc & (c1 | c2));
      uint32_t leg = erow & (eu | ed | el | er_);
      const uint32_t vul = mrow & L0 & ~L1;  // liberty count == 1
      t = __shfl(vul, lane - 1, 64);
      const uint32_t vu = (r > 0) ? t : 0u;
      t = __shfl(vul, lane + 1, 64);
      const uint32_t vd = (r < 18) ? t : 0u;
      leg |= erow & (vu | vd | ((vul << 1) & M19) | (vul >> 1));
      if (kk.x == r) leg &= ~(1u << kk.y);

      if (vl)
        pl64[lb * P64 + r] = spr3(L0) | (spr3(L1) << 1) | (spr3(L2) << 2);

      uint32_t g = runfill(vul, mrow);
      for (int it = 0; it < 90; ++it) {
        t = __shfl(g, lane - 1, 64);
        const uint32_t gu = (r > 0) ? t : 0u;
        t = __shfl(g, lane + 1, 64);
        const uint32_t gd = (r < 18) ? t : 0u;
        const uint32_t gn = runfill(g | ((gu | gd) & mrow), mrow);
        if (!__any(gn != g)) break;
        g = gn;
      }
      if (vl) pl64[lb * P64 + 19 + r] = spr2(leg) | (spr2(g) << 1);
    }

    // ---- LIGHT barrier: LDS writes visible, prefetch vmcnt NOT drained ----
    asm volatile("s_waitcnt lgkmcnt(0)" ::: "memory");
    __builtin_amdgcn_s_barrier();

    // ---- expand packed planes -> plain float4 stores ----------------------
    {
      const int nq = nb * NP / 4;  // nb in {12,4}: always divisible
      f32x4* s0 = (f32x4*)(out + (size_t)b0 * NP);
      f32x4* s1 = (f32x4*)(out + NB + (size_t)b0 * NP);
      f32x4* s2 = (f32x4*)(out + 2 * NB + (size_t)b0 * NP);
      for (int q = threadIdx.x; q < nq; q += TPB) {
        f32x4 t0, t1, t2;
#pragma unroll
        for (int j = 0; j < 4; ++j) {
          const int id = q * 4 + j;
          const int lb = (int)(((uint64_t)id * 5948986ull) >> 31);  // id/361
          const int p = id - lb * NP;
          const int r = (p * 27) >> 9;  // p/19 for p<512
          const int cc2 = p - r * WW;
          const uint64_t lib = pl64[lb * P64 + r];
          const uint64_t lg = pl64[lb * P64 + 19 + r];
          t0[j] = (float)((uint32_t)(lib >> (3 * cc2)) & 7u);
          const uint32_t lgv = (uint32_t)(lg >> (2 * cc2));
          t1[j] = (float)(lgv & 1u);
          t2[j] = (float)((lgv >> 1) & 1u);
        }
        s0[q] = t0;
        s1[q] = t1;
        s2[q] = t2;
      }
      const int rem0 = nq * 4;
      for (int id = rem0 + threadIdx.x; id < nb * NP; id += TPB) {
        const int lb = (int)(((uint64_t)id * 5948986ull) >> 31);
        const int p = id - lb * NP;
        const int r = (p * 27) >> 9;
        const int cc2 = p - r * WW;
        const uint64_t lib = pl64[lb * P64 + r];
        const uint64_t lg = pl64[lb * P64 + 19 + r];
        out[(size_t)b0 * NP + id] = (float)((uint32_t)(lib >> (3 * cc2)) & 7u);
        const uint32_t lgv = (uint32_t)(lg >> (2 * cc2));
        out[NB + (size_t)b0 * NP + id] = (float)(lgv & 1u);
        out[2 * NB + (size_t)b0 * NP + id] = (float)((lgv >> 1) & 1u);
      }
    }

    // ---- FULL barrier: next chunk staged; planes/stg free for reuse -------
    __syncthreads();
    bufc ^= 1;
  }
}

extern "C" void kernel_launch(void* const* d_in, const int* in_sizes, int n_in,
                              void* d_out, int out_size, void* d_ws,
                              size_t ws_size, hipStream_t stream) {
  const float* stones = (const float*)d_in[0];
  const int* cur = (const int*)d_in[1];
  const int* ko = (const int*)d_in[2];
  const int* zob = (const int*)d_in[3];
  const int* zturn = (const int*)d_in[4];
  const int* phash = (const int*)d_in[5];
  float* out = (float*)d_out;

  const int B = in_sizes[0] / (2 * NP);
  const int NCH = (B + BPB - 1) / BPB;
  const int blocks = min(GRID, NCH);
  go_pipe<<<blocks, TPB, 0, stream>>>(stones, cur, ko, zob, zturn, phash, out,
                                      B);
}

// Round 15
// 28.862 us; speedup vs baseline: 1.0711x; 1.0711x over previous
//
#include <hip/hip_runtime.h>
#include <stdint.h>

#define WW 19
#define NP 361
#define M19 0x7FFFFu
#define BPW 3                 // boards per wave in row phase (3*19 = 57 lanes)
#define BPB 12                // boards per block
#define TPB 256
#define STGF (BPB * 722)      // 8664 staged floats
#define P64 40                // u64 stride per board: 19 lib + 19 lg + 2 pad

typedef float f32x4 __attribute__((ext_vector_type(4)));

__device__ __forceinline__ uint32_t rev19(uint32_t x) { return __brev(x) >> 13; }

// Fill every horizontal run of m containing a seed of g (g subset of m).
__device__ __forceinline__ uint32_t runfill(uint32_t g, uint32_t m) {
  const uint32_t up = g | (m & ((m + g) ^ m ^ g));
  const uint32_t rm = rev19(m);
  const uint32_t rg = rev19(g);
  const uint32_t dn = rg | (rm & ((rm + rg) ^ rm ^ rg));
  return up | rev19(dn);
}

// Bit-spread: 19-bit mask -> every 3rd bit of a 57-bit value (Morton-3).
__device__ __forceinline__ uint64_t spr3(uint32_t v) {
  uint64_t x = v;
  x = (x | (x << 32)) & 0x1f00000000ffffull;
  x = (x | (x << 16)) & 0x1f0000ff0000ffull;
  x = (x | (x << 8)) & 0x100f00f00f00f00full;
  x = (x | (x << 4)) & 0x10c30c30c30c30c3ull;
  x = (x | (x << 2)) & 0x1249249249249249ull;
  return x;
}
// Bit-spread: 19-bit mask -> every 2nd bit (Morton-2).
__device__ __forceinline__ uint64_t spr2(uint32_t v) {
  uint64_t x = v;
  x = (x | (x << 16)) & 0x0000ffff0000ffffull;
  x = (x | (x << 8)) & 0x00ff00ff00ff00ffull;
  x = (x | (x << 4)) & 0x0f0f0f0f0f0f0f0full;
  x = (x | (x << 2)) & 0x3333333333333333ull;
  x = (x | (x << 1)) & 0x5555555555555555ull;
  return x;
}

__global__ __launch_bounds__(TPB, 4) void go_fused(
    const float* __restrict__ stones, const int* __restrict__ cur,
    const int* __restrict__ ko, const int* __restrict__ zob,
    const int* __restrict__ zturn, const int* __restrict__ phash,
    float* __restrict__ out, int B) {
  __shared__ float stg[STGF];            // raw staged stone floats (12 boards)
  __shared__ uint64_t pl64[BPB * P64];   // packed planes: lib3 | leg,grp

  const int wid = threadIdx.x >> 6;
  const int lane = threadIdx.x & 63;
  const int b0 = blockIdx.x * BPB;
  const int nb = min(BPB, B - b0);
  const size_t NB = (size_t)B * NP;

  // ---------------- phase 1: async global->LDS staging (raw floats) ---------
  {
    const float* gsrc = stones + (size_t)b0 * 722;
    if (nb == BPB) {
      // Full chunk: unpredicated (8664 floats; last round covers 8192..8663
      // plus 360 floats of overrun into LDS slack -- see static_assert below).
#pragma unroll
      for (int rnd = 0; rnd < 9; ++rnd) {
        const uint32_t fo = (uint32_t)rnd * 1024u + (uint32_t)wid * 256u +
                            (uint32_t)lane * 4u;
        if (rnd < 8 || fo < 8664u) {
          __builtin_amdgcn_global_load_lds(
              (const __attribute__((address_space(1))) uint32_t*)(gsrc + fo),
              (__attribute__((address_space(3))) uint32_t*)(stg + rnd * 1024 +
                                                            wid * 256),
              16, 0, 0);
        }
      }
    } else {
      const uint32_t nfl = (uint32_t)nb * 722u;
#pragma unroll
      for (int rnd = 0; rnd < 9; ++rnd) {
        const uint32_t fo = (uint32_t)rnd * 1024u + (uint32_t)wid * 256u +
                            (uint32_t)lane * 4u;
        if (fo < nfl) {
          __builtin_amdgcn_global_load_lds(
              (const __attribute__((address_space(1))) uint32_t*)(gsrc + fo),
              (__attribute__((address_space(3))) uint32_t*)(stg + rnd * 1024 +
                                                            wid * 256),
              16, 0, 0);
        }
      }
    }
  }

  // Zobrist tables preloaded into registers (uniform across blocks, cached).
  int zb[6], zw[6];
#pragma unroll
  for (int i = 0; i < 6; ++i) {
    const int p = i * 64 + lane;
    zb[i] = (p < NP) ? zob[p] : 0;
    zw[i] = (p < NP) ? zob[NP + p] : 0;
  }
  const int zt = zturn[0] ^ zturn[1];

  // Hoisted per-board loads: issue global latency under the staging drain.
  const int kq = (lane * 27) >> 9;  // lane / 19
  const int rq = lane - kq * WW;
  const int lbq = wid * BPW + kq;
  const int bq = b0 + lbq;
  const bool vlq = (lane < 57) && (lbq < nb);
  const int cpq = vlq ? cur[bq] : 0;
  int2 kkq = {-1, -1};
  if (vlq) kkq = ((const int2*)ko)[bq];

  __syncthreads();  // drains vmcnt; staged floats visible block-wide

  // ---------------- phase 1.5: zobrist hash from staged floats --------------
  {
    int hv[BPW];
#pragma unroll
    for (int k = 0; k < BPW; ++k) {
      const int lb = wid * BPW + k;
      const int base = lb * 722;
      int h = 0;
#pragma unroll
      for (int i = 0; i < 6; ++i) {
        const int cc = i * 64 + lane;
        if (cc < NP) {
          const uint32_t sb = stg[base + cc] > 0.5f;
          const uint32_t sw = stg[base + 361 + cc] > 0.5f;
          h ^= zb[i] & -(int)sb;
          h ^= zw[i] & -(int)sw;
        }
      }
      hv[k] = h;
    }
#pragma unroll
    for (int off = 32; off > 0; off >>= 1) {
#pragma unroll
      for (int k = 0; k < BPW; ++k) hv[k] ^= __shfl_xor(hv[k], off, 64);
    }
    if (lane == 0) {
#pragma unroll
      for (int k = 0; k < BPW; ++k) {
        const int b = b0 + wid * BPW + k;
        if (b < B) out[3 * NB + b] = (float)(phash[b] ^ hv[k] ^ zt);
      }
    }
  }

  // ---------------- phase 2: row-per-lane algebra + flood -> packed planes --
  {
    const int r = rq;
    const int lb = lbq;
    const bool vl = vlq;
    const int lbs = vl ? lb : 0;

    // Build this lane's black/white rows from staged floats.
    uint32_t brow = 0, wrow = 0;
    {
      const float* rb = &stg[lbs * 722 + r * WW];
#pragma unroll
      for (int c = 0; c < WW; ++c) {
        brow |= (uint32_t)(rb[c] > 0.5f) << c;
        wrow |= (uint32_t)(rb[361 + c] > 0.5f) << c;
      }
    }
    uint32_t mrow = (cpq == 0) ? wrow : brow;
    uint32_t erow = ~(brow | wrow) & M19;
    if (!vl) { mrow = 0; erow = 0; }

    // Liberties / legal / vulnerable (vertical neighbors via shfl).
    uint32_t t;
    t = __shfl(erow, lane - 1, 64);
    const uint32_t eu = (r > 0) ? t : 0u;
    t = __shfl(erow, lane + 1, 64);
    const uint32_t ed = (r < 18) ? t : 0u;
    const uint32_t el = (erow << 1) & M19;
    const uint32_t er_ = erow >> 1;
    const uint32_t s1 = eu ^ ed, c1 = eu & ed;
    const uint32_t s2 = el ^ er_, c2 = el & er_;
    const uint32_t cc = s1 & s2;
    const uint32_t L0 = s1 ^ s2;
    const uint32_t L1 = c1 ^ c2 ^ cc;
    const uint32_t L2 = (c1 & c2) | (cc & (c1 | c2));
    uint32_t leg = erow & (eu | ed | el | er_);
    const uint32_t vul = mrow & L0 & ~L1;  // liberty count == 1
    t = __shfl(vul, lane - 1, 64);
    const uint32_t vu = (r > 0) ? t : 0u;
    t = __shfl(vul, lane + 1, 64);
    const uint32_t vd = (r < 18) ? t : 0u;
    leg |= erow & (vu | vd | ((vul << 1) & M19) | (vul >> 1));
    if (kkq.x == r) leg &= ~(1u << kkq.y);

    // Pack + store liberty plane now (releases L0/L1/L2 before flood).
    if (vl)
      pl64[lb * P64 + r] = spr3(L0) | (spr3(L1) << 1) | (spr3(L2) << 2);

    // Flood fill: horizontal runfill + vertical shfl step, early exit.
    uint32_t g = runfill(vul, mrow);
    for (int it = 0; it < 90; ++it) {
      t = __shfl(g, lane - 1, 64);
      const uint32_t gu = (r > 0) ? t : 0u;
      t = __shfl(g, lane + 1, 64);
      const uint32_t gd = (r < 18) ? t : 0u;
      const uint32_t gn = runfill(g | ((gu | gd) & mrow), mrow);
      if (!__any(gn != g)) break;
      g = gn;
    }

    if (vl) pl64[lb * P64 + 19 + r] = spr2(leg) | (spr2(g) << 1);
  }
  __syncthreads();

  // ---------------- phase 3: expand packed planes -> plain float4 stores ----
  {
    const int nq = nb * NP / 4;  // nb in {12,4} -> always divisible
    f32x4* s0 = (f32x4*)(out + (size_t)b0 * NP);
    f32x4* s1 = (f32x4*)(out + NB + (size_t)b0 * NP);
    f32x4* s2 = (f32x4*)(out + 2 * NB + (size_t)b0 * NP);
    for (int q = threadIdx.x; q < nq; q += TPB) {
      f32x4 t0, t1, t2;
#pragma unroll
      for (int j = 0; j < 4; ++j) {
        const int id = q * 4 + j;
        const int lb = (int)(((uint64_t)id * 5948986ull) >> 31);  // id/361
        const int p = id - lb * NP;
        const int r = (p * 27) >> 9;  // p/19 for p<512
        const int c = p - r * WW;
        const uint64_t lib = pl64[lb * P64 + r];
        const uint64_t lg = pl64[lb * P64 + 19 + r];
        t0[j] = (float)((uint32_t)(lib >> (3 * c)) & 7u);
        const uint32_t lgv = (uint32_t)(lg >> (2 * c));
        t1[j] = (float)(lgv & 1u);
        t2[j] = (float)((lgv >> 1) & 1u);
      }
      s0[q] = t0;
      s1[q] = t1;
      s2[q] = t2;
    }
    // Generic remainder guard (never taken for nb in {12,4}; safety only).
    const int rem0 = nq * 4;
    for (int id = rem0 + threadIdx.x; id < nb * NP; id += TPB) {
      const int lb = (int)(((uint64_t)id * 5948986ull) >> 31);
      const int p = id - lb * NP;
      const int r = (p * 27) >> 9;
      const int c = p - r * WW;
      const uint64_t lib = pl64[lb * P64 + r];
      const uint64_t lg = pl64[lb * P64 + 19 + r];
      out[(size_t)b0 * NP + id] = (float)((uint32_t)(lib >> (3 * c)) & 7u);
      const uint32_t lgv = (uint32_t)(lg >> (2 * c));
      out[NB + (size_t)b0 * NP + id] = (float)(lgv & 1u);
      out[2 * NB + (size_t)b0 * NP + id] = (float)((lgv >> 1) & 1u);
    }
  }
}

// Staging overrun safety: the unpredicated full-chunk path's last round writes
// at most floats [8192, 8192+1024) but is guarded to stop at 8664; LDS beyond
// stg[8664] is pl64 (written only after __syncthreads), so no hazard.

extern "C" void kernel_launch(void* const* d_in, const int* in_sizes, int n_in,
                              void* d_out, int out_size, void* d_ws,
                              size_t ws_size, hipStream_t stream) {
  const float* stones = (const float*)d_in[0];
  const int* cur = (const int*)d_in[1];
  const int* ko = (const int*)d_in[2];
  const int* zob = (const int*)d_in[3];
  const int* zturn = (const int*)d_in[4];
  const int* phash = (const int*)d_in[5];
  float* out = (float*)d_out;

  const int B = in_sizes[0] / (2 * NP);
  const int blocks = (B + BPB - 1) / BPB;
  go_fused<<<blocks, TPB, 0, stream>>>(stones, cur, ko, zob, zturn, phash, out,
                                       B);
}